// Round 12
// baseline (658.310 us; speedup 1.0000x reference)
//
#include <hip/hip_runtime.h>
#include <hip/hip_bf16.h>
#include <math.h>

#define NBLK  256   // binning chunks/blocks (~100B per (bucket,block) stream)
#define SHIFT 7
#define BKT   128   // nodes per bucket
#define NBS   1024  // bucket slots (pow2 >= 782 used)

// ---------------- bf16 helpers (RNE) ----------------
__device__ __forceinline__ unsigned bfr(float x) {
  unsigned u = __float_as_uint(x);
  return (u + 0x7fffu + ((u >> 16) & 1u)) >> 16;
}
__device__ __forceinline__ unsigned bfpk(float lo, float hi) {
  return (bfr(hi) << 16) | bfr(lo);
}
__device__ __forceinline__ float bflo(unsigned u) { return __uint_as_float(u << 16); }
__device__ __forceinline__ float bfhi(unsigned u) { return __uint_as_float(u & 0xffff0000u); }

// ---------------- binned pair build (no global atomics, pow2 buckets) ----------------
__global__ __launch_bounds__(1024) void k_bin_count(const int* __restrict__ ei,
    int E, int ET, int chunk, int* __restrict__ A) {
  __shared__ int lh[NBS];
  int t = threadIdx.x;
  lh[t] = 0;
  __syncthreads();
  int beg = blockIdx.x * chunk, end = min(beg + chunk, ET);
  for (int i = beg + t; i < end; i += 1024) {
    int d = (i < E) ? ei[E + i] : (i - E);      // self loop for i>=E
    atomicAdd(&lh[d >> SHIFT], 1);
  }
  __syncthreads();
  A[t * NBLK + blockIdx.x] = lh[t];
}

// block-sum of 1024 consecutive ints (4 per thread)
__global__ void k_reduce4(const int* __restrict__ a, int* bsum, int n) {
  int t = threadIdx.x;
  int base = blockIdx.x * 1024 + t * 4;
  int v = 0;
  if (base + 3 < n) {
    int4 q = *reinterpret_cast<const int4*>(a + base);
    v = q.x + q.y + q.z + q.w;
  }
  #pragma unroll
  for (int off = 32; off; off >>= 1) v += __shfl_down(v, off, 64);
  __shared__ int sh[4];
  if ((t & 63) == 0) sh[t >> 6] = v;
  __syncthreads();
  if (t == 0) bsum[blockIdx.x] = sh[0] + sh[1] + sh[2] + sh[3];
}

// single-block inclusive->exclusive scan of block sums (nb <= 512)
__global__ void k_scan_bsum(int* bsum, int nb) {
  __shared__ int sh[512];
  int t = threadIdx.x;
  int v = (t < nb) ? bsum[t] : 0;
  sh[t] = v; __syncthreads();
  for (int off = 1; off < 512; off <<= 1) {
    int add = (t >= off) ? sh[t - off] : 0;
    __syncthreads();
    sh[t] += add;
    __syncthreads();
  }
  if (t < nb) bsum[t] = sh[t] - v;   // exclusive
}

// in-place exclusive scan apply, 4 elems/thread; writes A[n] = total
__global__ void k_scan_apply4(int* A, const int* __restrict__ bsum, int n) {
  __shared__ int sh[256];
  int t = threadIdx.x;
  int base = blockIdx.x * 1024 + t * 4;
  int4 q = *reinterpret_cast<const int4*>(A + base);   // n multiple of 1024
  int tsum = q.x + q.y + q.z + q.w;
  sh[t] = tsum; __syncthreads();
  for (int off = 1; off < 256; off <<= 1) {
    int add = (t >= off) ? sh[t - off] : 0;
    __syncthreads();
    sh[t] += add;
    __syncthreads();
  }
  int excl = sh[t] - tsum + bsum[blockIdx.x];
  int4 w;
  w.x = excl; w.y = w.x + q.x; w.z = w.y + q.y; w.w = w.z + q.z;
  *reinterpret_cast<int4*>(A + base) = w;
  if (base + 4 == n) A[n] = w.w + q.w;
}

__global__ __launch_bounds__(1024) void k_bin_scatter(const int* __restrict__ ei,
    int E, int ET, int chunk, const int* __restrict__ A, int* __restrict__ pairs) {
  __shared__ int cur[NBS];
  int t = threadIdx.x;
  cur[t] = A[t * NBLK + blockIdx.x];
  __syncthreads();
  int beg = blockIdx.x * chunk, end = min(beg + chunk, ET);
  for (int i = beg + t; i < end; i += 1024) {
    int s, d;
    if (i < E) { s = ei[i]; d = ei[E + i]; } else { s = d = i - E; }
    int pos = atomicAdd(&cur[d >> SHIFT], 1);
    pairs[pos] = (s << SHIFT) | (d & (BKT - 1));   // src < 2^25
  }
}

// ----- layer 1 transform: xl1(bf16) = x@W1l, xr1(f32) = x@W1r -----
__global__ __launch_bounds__(256) void k_gemm1(const float* __restrict__ x,
    const float* __restrict__ Wl, const float* __restrict__ Wr,
    unsigned* __restrict__ xlb, float* __restrict__ xr, int n) {
  __shared__ float xs[64 * 132];
  __shared__ float Ws[128 * 32];
  int t = threadIdx.x;
  int r0 = blockIdx.x * 64;
  #pragma unroll
  for (int i = 0; i < 8; i++) {
    int idx = t + i * 256;
    int k = idx >> 4, c = idx & 15;
    Ws[k * 32 + c]      = Wl[idx];
    Ws[k * 32 + 16 + c] = Wr[idx];
  }
  #pragma unroll
  for (int i = 0; i < 8; i++) {
    int v = t + i * 256;
    int row = v >> 5;
    int col4 = v & 31;
    float4 val = make_float4(0.f, 0.f, 0.f, 0.f);
    if (r0 + row < n)
      val = reinterpret_cast<const float4*>(x)[(long)(r0 + row) * 32 + col4];
    float* dst = &xs[row * 132 + col4 * 4];
    dst[0] = val.x; dst[1] = val.y; dst[2] = val.z; dst[3] = val.w;
  }
  __syncthreads();
  int g = t >> 2;
  int sub = t & 3;
  float acc[8] = {0.f,0.f,0.f,0.f,0.f,0.f,0.f,0.f};
  #pragma unroll 4
  for (int k = 0; k < 128; k++) {
    float xv = xs[g * 132 + k];
    const float4* wp = reinterpret_cast<const float4*>(&Ws[k * 32 + sub * 8]);
    float4 w0 = wp[0], w1 = wp[1];
    acc[0] += xv * w0.x; acc[1] += xv * w0.y; acc[2] += xv * w0.z; acc[3] += xv * w0.w;
    acc[4] += xv * w1.x; acc[5] += xv * w1.y; acc[6] += xv * w1.z; acc[7] += xv * w1.w;
  }
  int row = r0 + g;
  if (row < n) {
    if (sub < 2) {
      uint4 pk;
      pk.x = bfpk(acc[0], acc[1]); pk.y = bfpk(acc[2], acc[3]);
      pk.z = bfpk(acc[4], acc[5]); pk.w = bfpk(acc[6], acc[7]);
      reinterpret_cast<uint4*>(xlb)[(long)row * 2 + sub] = pk;
    } else {
      float4* o4 = reinterpret_cast<float4*>(&xr[(long)row * 16 + (sub - 2) * 8]);
      o4[0] = make_float4(acc[0], acc[1], acc[2], acc[3]);
      o4[1] = make_float4(acc[4], acc[5], acc[6], acc[7]);
    }
  }
}

// ------- layer-1: edge-streaming per bucket, LDS f32-atomic accumulators, fused gemm2 -------
// No max-shift needed: scores |e| <~ 14 (clamped at 60); softmax == reference exactly
// up to f32 rounding. leaky(z) = 0.6z + 0.4|z| (slope 0.2).
__global__ __launch_bounds__(512) void k_edge1_bucket(const int* __restrict__ pairs,
    const int* __restrict__ A, const unsigned* __restrict__ xlb,
    const float* __restrict__ xr, const float* __restrict__ att,
    const float* __restrict__ bias, const float* __restrict__ W2l,
    const float* __restrict__ W2r, unsigned* __restrict__ xl2b,
    float* __restrict__ xr2, int N) {
  __shared__ float acc[BKT][18];   // [s, nu0..15, pad]
  __shared__ float xrs[BKT][20];   // staged xr rows (pad to 80B: aligned, bank-spread)
  __shared__ float Ws[256];        // [k][j]: j<8 W2l, j>=8 W2r
  __shared__ float bs[16];
  int b = blockIdx.x, t = threadIdx.x;
  int node0 = b << SHIFT;
  int nloc = min(BKT, N - node0);
  for (int i = t; i < BKT * 18; i += 512) ((float*)acc)[i] = 0.f;
  if (t < 128) { int k = t >> 3, j = t & 7; Ws[k*16+j] = W2l[t]; Ws[k*16+8+j] = W2r[t]; }
  if (t < 16) bs[t] = bias[t];
  for (int i = t; i < nloc * 4; i += 512) {
    int node = i >> 2, q = i & 3;
    float4 v = reinterpret_cast<const float4*>(xr + (long)(node0 + node) * 16)[q];
    float* dst = &xrs[node][q * 4];
    dst[0] = v.x; dst[1] = v.y; dst[2] = v.z; dst[3] = v.w;
  }
  float av[16];
  #pragma unroll
  for (int c = 0; c < 16; c++) av[c] = att[c];
  int base = A[b * NBLK], endp = A[(b + 1) * NBLK];
  __syncthreads();

  for (int e = base + t; e < endp; e += 512) {
    int p = pairs[e];
    int src = ((unsigned)p) >> SHIFT;
    int d = p & (BKT - 1);
    const uint4* q = reinterpret_cast<const uint4*>(xlb + (long)src * 8);
    uint4 ra = q[0], rb = q[1];
    unsigned uu[8] = {ra.x, ra.y, ra.z, ra.w, rb.x, rb.y, rb.z, rb.w};
    float xlv[16];
    #pragma unroll
    for (int k = 0; k < 8; k++) { xlv[2*k] = bflo(uu[k]); xlv[2*k+1] = bfhi(uu[k]); }
    const float4* xn4 = reinterpret_cast<const float4*>(xrs[d]);
    float4 x0 = xn4[0], x1 = xn4[1], x2 = xn4[2], x3 = xn4[3];
    float xn[16] = {x0.x,x0.y,x0.z,x0.w, x1.x,x1.y,x1.z,x1.w,
                    x2.x,x2.y,x2.z,x2.w, x3.x,x3.y,x3.z,x3.w};
    float e1 = 0.f, e2 = 0.f;
    #pragma unroll
    for (int c = 0; c < 16; c++) {
      float z = xlv[c] + xn[c];
      e1 += av[c] * z;
      e2 += av[c] * fabsf(z);
    }
    float pe = __expf(fminf(0.6f * e1 + 0.4f * e2, 60.f));
    float* ad = acc[d];
    atomicAdd(&ad[0], pe);
    #pragma unroll
    for (int c = 0; c < 16; c++) atomicAdd(&ad[1 + c], pe * xlv[c]);
  }
  __syncthreads();

  if (t < nloc) {
    float inv = 1.f / fmaxf(acc[t][0], 1e-16f);
    float o[16];
    #pragma unroll
    for (int c = 0; c < 16; c++) o[c] = fmaxf(acc[t][1 + c] * inv + bs[c], 0.f);
    float l2[8] = {0,0,0,0,0,0,0,0}, r2[8] = {0,0,0,0,0,0,0,0};
    #pragma unroll
    for (int k = 0; k < 16; k++) {
      float ok = o[k];
      #pragma unroll
      for (int j = 0; j < 8; j++) {
        l2[j] += ok * Ws[k * 16 + j];
        r2[j] += ok * Ws[k * 16 + 8 + j];
      }
    }
    int node = node0 + t;
    uint4 pk;
    pk.x = bfpk(l2[0], l2[1]); pk.y = bfpk(l2[2], l2[3]);
    pk.z = bfpk(l2[4], l2[5]); pk.w = bfpk(l2[6], l2[7]);
    reinterpret_cast<uint4*>(xl2b)[node] = pk;
    float4* pr = reinterpret_cast<float4*>(xr2 + (long)node * 8);
    pr[0] = make_float4(r2[0], r2[1], r2[2], r2[3]);
    pr[1] = make_float4(r2[4], r2[5], r2[6], r2[7]);
  }
}

// ------- layer-2: edge-streaming per bucket, 8 channels -------
__global__ __launch_bounds__(512) void k_edge2_bucket(const int* __restrict__ pairs,
    const int* __restrict__ A, const unsigned* __restrict__ xlb,
    const float* __restrict__ xr, const float* __restrict__ att,
    const float* __restrict__ bias, float* __restrict__ out, int N) {
  __shared__ float acc[BKT][10];   // [s, nu0..7, pad]
  __shared__ float xrs[BKT][12];   // staged xr2 rows (48B stride: aligned)
  __shared__ float bs[8];
  int b = blockIdx.x, t = threadIdx.x;
  int node0 = b << SHIFT;
  int nloc = min(BKT, N - node0);
  for (int i = t; i < BKT * 10; i += 512) ((float*)acc)[i] = 0.f;
  if (t < 8) bs[t] = bias[t];
  for (int i = t; i < nloc * 2; i += 512) {
    int node = i >> 1, q = i & 1;
    float4 v = reinterpret_cast<const float4*>(xr + (long)(node0 + node) * 8)[q];
    float* dst = &xrs[node][q * 4];
    dst[0] = v.x; dst[1] = v.y; dst[2] = v.z; dst[3] = v.w;
  }
  float av[8];
  #pragma unroll
  for (int c = 0; c < 8; c++) av[c] = att[c];
  int base = A[b * NBLK], endp = A[(b + 1) * NBLK];
  __syncthreads();

  for (int e = base + t; e < endp; e += 512) {
    int p = pairs[e];
    int src = ((unsigned)p) >> SHIFT;
    int d = p & (BKT - 1);
    uint4 ra = reinterpret_cast<const uint4*>(xlb)[src];
    unsigned uu[4] = {ra.x, ra.y, ra.z, ra.w};
    float xlv[8];
    #pragma unroll
    for (int k = 0; k < 4; k++) { xlv[2*k] = bflo(uu[k]); xlv[2*k+1] = bfhi(uu[k]); }
    const float4* xn4 = reinterpret_cast<const float4*>(xrs[d]);
    float4 x0 = xn4[0], x1 = xn4[1];
    float xn[8] = {x0.x,x0.y,x0.z,x0.w, x1.x,x1.y,x1.z,x1.w};
    float e1 = 0.f, e2 = 0.f;
    #pragma unroll
    for (int c = 0; c < 8; c++) {
      float z = xlv[c] + xn[c];
      e1 += av[c] * z;
      e2 += av[c] * fabsf(z);
    }
    float pe = __expf(fminf(0.6f * e1 + 0.4f * e2, 60.f));
    float* ad = acc[d];
    atomicAdd(&ad[0], pe);
    #pragma unroll
    for (int c = 0; c < 8; c++) atomicAdd(&ad[1 + c], pe * xlv[c]);
  }
  __syncthreads();

  if (t < nloc) {
    float inv = 1.f / fmaxf(acc[t][0], 1e-16f);
    int node = node0 + t;
    float o[8];
    #pragma unroll
    for (int c = 0; c < 8; c++) o[c] = fmaxf(acc[t][1 + c] * inv + bs[c], 0.f);
    float4* po = reinterpret_cast<float4*>(out + (long)node * 8);
    po[0] = make_float4(o[0], o[1], o[2], o[3]);
    po[1] = make_float4(o[4], o[5], o[6], o[7]);
  }
}

// ---------------- fused mean pool + linear: one block per graph ----------------
__global__ __launch_bounds__(256) void k_pool_final(const float* __restrict__ h,
    const int* __restrict__ batch, const float* __restrict__ Wlin,
    const float* __restrict__ blin, float* __restrict__ out, int n) {
  int g = blockIdx.x;
  int lo = 0, hi = n;
  while (lo < hi) { int mid = (lo + hi) >> 1; if (batch[mid] < g) lo = mid + 1; else hi = mid; }
  int beg = lo;
  hi = n;
  while (lo < hi) { int mid = (lo + hi) >> 1; if (batch[mid] < g + 1) lo = mid + 1; else hi = mid; }
  int end = lo;

  float w[8];
  #pragma unroll
  for (int c = 0; c < 8; c++) w[c] = Wlin[c];

  float acc = 0.f;
  int t = threadIdx.x;
  for (int i = beg + t; i < end; i += 256) {
    const float4* hp = reinterpret_cast<const float4*>(h + (long)i * 8);
    float4 v0 = hp[0], v1 = hp[1];
    acc += v0.x * w[0] + v0.y * w[1] + v0.z * w[2] + v0.w * w[3]
         + v1.x * w[4] + v1.y * w[5] + v1.z * w[6] + v1.w * w[7];
  }
  #pragma unroll
  for (int off = 32; off; off >>= 1) acc += __shfl_down(acc, off, 64);
  __shared__ float sh[4];
  if ((t & 63) == 0) sh[t >> 6] = acc;
  __syncthreads();
  if (t == 0) {
    float total = sh[0] + sh[1] + sh[2] + sh[3];
    float cnt = (float)(end - beg);
    out[g] = total / fmaxf(cnt, 1.f) + blin[0];
  }
}

extern "C" void kernel_launch(void* const* d_in, const int* in_sizes, int n_in,
                              void* d_out, int out_size, void* d_ws, size_t ws_size,
                              hipStream_t stream) {
  (void)n_in; (void)ws_size;
  const float* x    = (const float*)d_in[0];
  const int*   ei   = (const int*)d_in[1];
  const int*   batch= (const int*)d_in[2];
  const float* W1l  = (const float*)d_in[3];
  const float* W1r  = (const float*)d_in[4];
  const float* a1   = (const float*)d_in[5];
  const float* b1   = (const float*)d_in[6];
  const float* W2l  = (const float*)d_in[7];
  const float* W2r  = (const float*)d_in[8];
  const float* a2   = (const float*)d_in[9];
  const float* b2   = (const float*)d_in[10];
  const float* Wlin = (const float*)d_in[11];
  const float* blin = (const float*)d_in[12];
  float* out = (float*)d_out;

  int N = in_sizes[0] / 128;
  int E = in_sizes[1] / 2;
  int G = out_size;                    // 256 graphs
  int ET = E + N;                      // edges incl self loops
  int NBu = (N + BKT - 1) >> SHIFT;    // used buckets (128 nodes each) = 782
  int chunk = (ET + NBLK - 1) / NBLK;
  int nA = NBS * NBLK;                 // 262144

  char* ws = (char*)d_ws;
  size_t off = 0;
  auto alloc = [&](size_t bytes) {
    void* p = ws + off; off = (off + bytes + 255) & ~(size_t)255; return p;
  };
  int* A        = (int*)alloc((size_t)(nA + 1) * 4);
  int* bsum     = (int*)alloc(512 * 4);
  int* pairs    = (int*)alloc((size_t)ET * 4);          // kept live through edge kernels
  unsigned* xl1b= (unsigned*)alloc((size_t)N * 32);     // bf16 x16
  float* xr1    = (float*)alloc((size_t)N * 64);        // f32 x16
  unsigned* xl2b= (unsigned*)alloc((size_t)N * 16);     // bf16 x8
  float* xr2    = (float*)alloc((size_t)N * 32);        // f32 x8
  float* h2     = (float*)alloc((size_t)N * 32);        // f32 x8

  k_bin_count<<<NBLK, 1024, 0, stream>>>(ei, E, ET, chunk, A);
  k_reduce4<<<nA / 1024, 256, 0, stream>>>(A, bsum, nA);
  k_scan_bsum<<<1, 512, 0, stream>>>(bsum, nA / 1024);
  k_scan_apply4<<<nA / 1024, 256, 0, stream>>>(A, bsum, nA);
  k_bin_scatter<<<NBLK, 1024, 0, stream>>>(ei, E, ET, chunk, A, pairs);
  k_gemm1<<<(N + 63) / 64, 256, 0, stream>>>(x, W1l, W1r, xl1b, xr1, N);
  k_edge1_bucket<<<NBu, 512, 0, stream>>>(pairs, A, xl1b, xr1, a1, b1,
                                          W2l, W2r, xl2b, xr2, N);
  k_edge2_bucket<<<NBu, 512, 0, stream>>>(pairs, A, xl2b, xr2, a2, b2, h2, N);
  k_pool_final<<<G, 256, 0, stream>>>(h2, batch, Wlin, blin, out, N);
}

// Round 13
// 154.735 us; speedup vs baseline: 4.2544x; 4.2544x over previous
//
#include <hip/hip_runtime.h>
#include <hip/hip_bf16.h>
#include <math.h>

#define NBLK 256   // binning chunks/blocks (keeps ~100B per (bucket,block) stream)
#define NBS  512   // bucket slots (pow2 bucket = 256 nodes => 391 used)

typedef float v2f __attribute__((ext_vector_type(2)));

// ---------------- bf16 helpers (RNE) ----------------
__device__ __forceinline__ unsigned bfr(float x) {      // f32 -> bf16 bits (RNE)
  unsigned u = __float_as_uint(x);
  return (u + 0x7fffu + ((u >> 16) & 1u)) >> 16;
}
__device__ __forceinline__ unsigned bfpk(float lo, float hi) {
  return (bfr(hi) << 16) | bfr(lo);
}
__device__ __forceinline__ float bflo(unsigned u) { return __uint_as_float(u << 16); }
__device__ __forceinline__ float bfhi(unsigned u) { return __uint_as_float(u & 0xffff0000u); }

// ---------------- binned CSR build (no global atomics, pow2 buckets) ----------------
__global__ __launch_bounds__(1024) void k_bin_count(const int* __restrict__ ei,
    int E, int ET, int chunk, int* __restrict__ A) {
  __shared__ int lh[NBS];
  int t = threadIdx.x;
  if (t < NBS) lh[t] = 0;
  __syncthreads();
  int beg = blockIdx.x * chunk, end = min(beg + chunk, ET);
  for (int i = beg + t; i < end; i += 1024) {
    int d = (i < E) ? ei[E + i] : (i - E);      // self loop for i>=E
    atomicAdd(&lh[d >> 8], 1);
  }
  __syncthreads();
  if (t < NBS) A[t * NBLK + blockIdx.x] = lh[t];
}

// block-sum of 1024 consecutive ints (4 per thread)
__global__ void k_reduce4(const int* __restrict__ a, int* bsum, int n) {
  int t = threadIdx.x;
  int base = blockIdx.x * 1024 + t * 4;
  int v = 0;
  if (base + 3 < n) {
    int4 q = *reinterpret_cast<const int4*>(a + base);
    v = q.x + q.y + q.z + q.w;
  } else {
    for (int k = 0; k < 4; k++) if (base + k < n) v += a[base + k];
  }
  #pragma unroll
  for (int off = 32; off; off >>= 1) v += __shfl_down(v, off, 64);
  __shared__ int sh[4];
  if ((t & 63) == 0) sh[t >> 6] = v;
  __syncthreads();
  if (t == 0) bsum[blockIdx.x] = sh[0] + sh[1] + sh[2] + sh[3];
}

// single-block inclusive->exclusive scan of block sums (nb <= 512)
__global__ void k_scan_bsum(int* bsum, int nb) {
  __shared__ int sh[512];
  int t = threadIdx.x;
  int v = (t < nb) ? bsum[t] : 0;
  sh[t] = v; __syncthreads();
  for (int off = 1; off < 512; off <<= 1) {
    int add = (t >= off) ? sh[t - off] : 0;
    __syncthreads();
    sh[t] += add;
    __syncthreads();
  }
  if (t < nb) bsum[t] = sh[t] - v;   // exclusive
}

// in-place exclusive scan apply, 4 elems/thread; writes A[n] = total
__global__ void k_scan_apply4(int* A, const int* __restrict__ bsum, int n) {
  __shared__ int sh[256];
  int t = threadIdx.x;
  int base = blockIdx.x * 1024 + t * 4;
  int4 q = *reinterpret_cast<const int4*>(A + base);   // n is multiple of 1024
  int tsum = q.x + q.y + q.z + q.w;
  sh[t] = tsum; __syncthreads();
  for (int off = 1; off < 256; off <<= 1) {
    int add = (t >= off) ? sh[t - off] : 0;
    __syncthreads();
    sh[t] += add;
    __syncthreads();
  }
  int excl = sh[t] - tsum + bsum[blockIdx.x];
  int4 w;
  w.x = excl; w.y = w.x + q.x; w.z = w.y + q.y; w.w = w.z + q.z;
  *reinterpret_cast<int4*>(A + base) = w;
  if (base + 4 == n) A[n] = w.w + q.w;
}

__global__ __launch_bounds__(1024) void k_bin_scatter(const int* __restrict__ ei,
    int E, int ET, int chunk, const int* __restrict__ A, int* __restrict__ pairs) {
  __shared__ int cur[NBS];
  int t = threadIdx.x;
  if (t < NBS) cur[t] = A[t * NBLK + blockIdx.x];
  __syncthreads();
  int beg = blockIdx.x * chunk, end = min(beg + chunk, ET);
  for (int i = beg + t; i < end; i += 1024) {
    int s, d;
    if (i < E) { s = ei[i]; d = ei[E + i]; } else { s = d = i - E; }
    int pos = atomicAdd(&cur[d >> 8], 1);
    pairs[pos] = (s << 8) | (d & 255);        // src<2^24, local dst in 8 bits
  }
}

__global__ __launch_bounds__(1024) void k_csr_build(const int* __restrict__ pairs,
    const int* __restrict__ A, int* __restrict__ csr_ptr, int* __restrict__ csr_src,
    int N, int NBu) {
  __shared__ int cnt[256];
  __shared__ int cur[256];
  __shared__ int sh[256];
  int b = blockIdx.x, t = threadIdx.x;
  int base = A[b * NBLK], endp = A[(b + 1) * NBLK];
  int node0 = b << 8;
  if (t < 256) cnt[t] = 0;
  __syncthreads();
  for (int e = base + t; e < endp; e += 1024)
    atomicAdd(&cnt[pairs[e] & 255], 1);
  __syncthreads();
  int v = (t < 256) ? cnt[t] : 0;
  if (t < 256) sh[t] = v;
  __syncthreads();
  for (int off = 1; off < 256; off <<= 1) {
    int add = (t >= off && t < 256) ? sh[t - off] : 0;
    __syncthreads();
    if (t < 256) sh[t] += add;
    __syncthreads();
  }
  if (t < 256) {
    int excl = sh[t] - v;
    if (node0 + t < N) csr_ptr[node0 + t] = base + excl;
    cur[t] = base + excl;
  }
  if (b == NBu - 1 && t == 0) csr_ptr[N] = endp;
  __syncthreads();
  for (int e = base + t; e < endp; e += 1024) {
    int p = pairs[e];
    int pos = atomicAdd(&cur[p & 255], 1);
    csr_src[pos] = ((unsigned)p) >> 8;
  }
}

// ----- layer 1 transform: xl1(bf16) = x@W1l, xr1(f32) = x@W1r -----
__global__ __launch_bounds__(256) void k_gemm1(const float* __restrict__ x,
    const float* __restrict__ Wl, const float* __restrict__ Wr,
    unsigned* __restrict__ xlb, float* __restrict__ xr, int n) {
  __shared__ float xs[64 * 132];
  __shared__ float Ws[128 * 32];
  int t = threadIdx.x;
  int r0 = blockIdx.x * 64;
  #pragma unroll
  for (int i = 0; i < 8; i++) {
    int idx = t + i * 256;
    int k = idx >> 4, c = idx & 15;
    Ws[k * 32 + c]      = Wl[idx];
    Ws[k * 32 + 16 + c] = Wr[idx];
  }
  #pragma unroll
  for (int i = 0; i < 8; i++) {
    int v = t + i * 256;
    int row = v >> 5;
    int col4 = v & 31;
    float4 val = make_float4(0.f, 0.f, 0.f, 0.f);
    if (r0 + row < n)
      val = reinterpret_cast<const float4*>(x)[(long)(r0 + row) * 32 + col4];
    float* dst = &xs[row * 132 + col4 * 4];
    dst[0] = val.x; dst[1] = val.y; dst[2] = val.z; dst[3] = val.w;
  }
  __syncthreads();
  int g = t >> 2;
  int sub = t & 3;
  float acc[8] = {0.f,0.f,0.f,0.f,0.f,0.f,0.f,0.f};
  #pragma unroll 4
  for (int k = 0; k < 128; k++) {
    float xv = xs[g * 132 + k];
    const float4* wp = reinterpret_cast<const float4*>(&Ws[k * 32 + sub * 8]);
    float4 w0 = wp[0], w1 = wp[1];
    acc[0] += xv * w0.x; acc[1] += xv * w0.y; acc[2] += xv * w0.z; acc[3] += xv * w0.w;
    acc[4] += xv * w1.x; acc[5] += xv * w1.y; acc[6] += xv * w1.z; acc[7] += xv * w1.w;
  }
  int row = r0 + g;
  if (row < n) {
    if (sub < 2) {       // xl channels sub*8 .. sub*8+7 as bf16
      uint4 pk;
      pk.x = bfpk(acc[0], acc[1]); pk.y = bfpk(acc[2], acc[3]);
      pk.z = bfpk(acc[4], acc[5]); pk.w = bfpk(acc[6], acc[7]);
      reinterpret_cast<uint4*>(xlb)[(long)row * 2 + sub] = pk;
    } else {             // xr channels (sub-2)*8 .. +7 as f32
      float4* o4 = reinterpret_cast<float4*>(&xr[(long)row * 16 + (sub - 2) * 8]);
      o4[0] = make_float4(acc[0], acc[1], acc[2], acc[3]);
      o4[1] = make_float4(acc[4], acc[5], acc[6], acc[7]);
    }
  }
}

// ---------------- octet DPP helpers (cross-lane within 8 lanes, VALU only) ----------------
template<int CTRL>
__device__ __forceinline__ float dpp_mov(float x) {
  return __int_as_float(__builtin_amdgcn_update_dpp(0, __float_as_int(x), CTRL, 0xF, 0xF, true));
}
__device__ __forceinline__ float oct_sum(float x) {
  x += dpp_mov<0xB1>(x);
  x += dpp_mov<0x4E>(x);
  x += dpp_mov<0x141>(x);
  return x;
}
__device__ __forceinline__ float oct_max(float x) {
  x = fmaxf(x, dpp_mov<0xB1>(x));
  x = fmaxf(x, dpp_mov<0x4E>(x));
  x = fmaxf(x, dpp_mov<0x141>(x));
  return x;
}

// ------- layer-1 edge aggregation: 8 lanes/node, bf16 gather, 3-slot pipeline, fused gemm2 -------
// leaky(z) = 0.6z + 0.4|z| (slope 0.2). Defer-max: m=0 unless e>m+25 (exact fallback).
// Inner chains use float2 ext-vectors to invite v_pk_add_f32/v_pk_fma_f32 emission.
__global__ __launch_bounds__(256) void k_edge1(const int* __restrict__ csr_ptr,
    const int* __restrict__ csr_src, const unsigned* __restrict__ xlb,
    const float* __restrict__ xr, const float* __restrict__ att,
    const float* __restrict__ bias, const float* __restrict__ W2l,
    const float* __restrict__ W2r, unsigned* __restrict__ xl2b,
    float* __restrict__ xr2, int n) {
  __shared__ float Ws[16 * 16];    // [k][j]: j<8 -> W2l, j>=8 -> W2r
  int t = threadIdx.x;
  if (t < 128) {
    int k = t >> 3, j = t & 7;
    Ws[k * 16 + j]     = W2l[t];
    Ws[k * 16 + 8 + j] = W2r[t];
  }
  __syncthreads();
  int node = blockIdx.x * 32 + (t >> 3);
  int sub = t & 7;
  if (node >= n) return;
  int beg = csr_ptr[node], end = csr_ptr[node + 1];
  v2f xrv[8], av6[8], av4[8], nu[8];
  const float4* xrp = reinterpret_cast<const float4*>(xr + (long)node * 16);
  #pragma unroll
  for (int q = 0; q < 2; q++) {
    float4 v0 = xrp[q * 2], v1 = xrp[q * 2 + 1];
    xrv[q*4]   = (v2f){v0.x, v0.y}; xrv[q*4+1] = (v2f){v0.z, v0.w};
    xrv[q*4+2] = (v2f){v1.x, v1.y}; xrv[q*4+3] = (v2f){v1.z, v1.w};
  }
  #pragma unroll
  for (int k = 0; k < 8; k++) {
    float a0 = att[2*k], a1 = att[2*k+1];
    av6[k] = (v2f){0.6f * a0, 0.6f * a1};
    av4[k] = (v2f){0.4f * a0, 0.4f * a1};
    nu[k] = (v2f){0.f, 0.f};
  }
  float m = 0.f, s = 0.f;

  auto PROCESS = [&](const uint4& ra, const uint4& rb) {
    unsigned uu[8] = {ra.x, ra.y, ra.z, ra.w, rb.x, rb.y, rb.z, rb.w};
    v2f xlv[8];
    #pragma unroll
    for (int k = 0; k < 8; k++) xlv[k] = (v2f){bflo(uu[k]), bfhi(uu[k])};
    v2f e1 = (v2f){0.f, 0.f}, e2 = (v2f){0.f, 0.f};
    #pragma unroll
    for (int k = 0; k < 8; k++) {
      v2f z = xlv[k] + xrv[k];
      v2f za = (v2f){__builtin_fabsf(z.x), __builtin_fabsf(z.y)};
      e1 = av6[k] * z + e1;
      e2 = av4[k] * za + e2;
    }
    float e = e1.x + e1.y + e2.x + e2.y;
    if (e > m + 25.f) {                       // rare exact rescale fallback
      float sc = __expf(m - e);
      s *= sc;
      v2f sc2 = (v2f){sc, sc};
      #pragma unroll
      for (int k = 0; k < 8; k++) nu[k] *= sc2;
      m = e;
    }
    float pe = __expf(e - m);
    s += pe;
    v2f pe2 = (v2f){pe, pe};
    #pragma unroll
    for (int k = 0; k < 8; k++) nu[k] = pe2 * xlv[k] + nu[k];
  };

  int i = beg + sub;
  int i3 = i + 24;                   // 3 slots x stride 8
  int x3 = 0;
  uint4 a0, b0, a1, b1, a2, b2;
  if (i < end) {
    const uint4* p = reinterpret_cast<const uint4*>(xlb + (long)csr_src[i] * 8);
    a0 = p[0]; b0 = p[1];
  }
  if (i + 8 < end) {
    const uint4* p = reinterpret_cast<const uint4*>(xlb + (long)csr_src[i + 8] * 8);
    a1 = p[0]; b1 = p[1];
  }
  if (i + 16 < end) {
    const uint4* p = reinterpret_cast<const uint4*>(xlb + (long)csr_src[i + 16] * 8);
    a2 = p[0]; b2 = p[1];
  }
  if (i3 < end) x3 = csr_src[i3];

  #define STEP1(AA, BB)                                                         \
    if (i >= end) break;                                                        \
    PROCESS(AA, BB);                                                            \
    if (i3 < end) {                                                             \
      const uint4* p = reinterpret_cast<const uint4*>(xlb + (long)x3 * 8);      \
      AA = p[0]; BB = p[1];                                                     \
    }                                                                           \
    i += 8; i3 += 8;                                                            \
    if (i3 < end) x3 = csr_src[i3];

  for (;;) {
    STEP1(a0, b0)
    STEP1(a1, b1)
    STEP1(a2, b2)
  }
  #undef STEP1

  // merge the 8 per-lane chains within the octet (exact)
  float M = oct_max(m);
  float sc = __expf(m - M);
  float S = oct_sum(s * sc);
  float o[16];
  #pragma unroll
  for (int k = 0; k < 8; k++) {
    o[2*k]   = oct_sum(nu[k].x * sc);
    o[2*k+1] = oct_sum(nu[k].y * sc);
  }
  float inv = 1.f / fmaxf(S, 1e-16f);
  #pragma unroll
  for (int c = 0; c < 16; c++) o[c] = fmaxf(o[c] * inv + bias[c], 0.f);  // relu(h1)
  // fused layer-2 transform: each lane computes 2 of the 16 output channels.
  // sub<4: xl2 channels (sub*2, sub*2+1); sub>=4: xr2 channels ((sub-4)*2, +1)
  int col = (sub < 4) ? (sub * 2) : (8 + (sub - 4) * 2);
  float r0 = 0.f, r1 = 0.f;
  #pragma unroll
  for (int k = 0; k < 16; k++) {
    float ok = o[k];
    r0 += ok * Ws[k * 16 + col];
    r1 += ok * Ws[k * 16 + col + 1];
  }
  if (sub < 4) {   // xl2 bf16: 2 vals -> 1 uint
    xl2b[(long)node * 4 + sub] = bfpk(r0, r1);
  } else {         // xr2 f32: float2
    reinterpret_cast<float2*>(xr2)[(long)node * 4 + (sub - 4)] = make_float2(r0, r1);
  }
}

// ------- layer-2 edge aggregation: 8 lanes/node, bf16 gather, 3-slot pipeline -------
__global__ __launch_bounds__(256) void k_edge2(const int* __restrict__ csr_ptr,
    const int* __restrict__ csr_src, const unsigned* __restrict__ xlb,
    const float* __restrict__ xr, const float* __restrict__ att,
    const float* __restrict__ bias, float* __restrict__ out, int n) {
  int t = threadIdx.x;
  int node = blockIdx.x * 32 + (t >> 3);
  int sub = t & 7;
  if (node >= n) return;
  int beg = csr_ptr[node], end = csr_ptr[node + 1];
  v2f xrv[4], av6[4], av4[4], nu[4];
  const float4* xrp = reinterpret_cast<const float4*>(xr + (long)node * 8);
  {
    float4 v0 = xrp[0], v1 = xrp[1];
    xrv[0] = (v2f){v0.x, v0.y}; xrv[1] = (v2f){v0.z, v0.w};
    xrv[2] = (v2f){v1.x, v1.y}; xrv[3] = (v2f){v1.z, v1.w};
  }
  #pragma unroll
  for (int k = 0; k < 4; k++) {
    float a0 = att[2*k], a1 = att[2*k+1];
    av6[k] = (v2f){0.6f * a0, 0.6f * a1};
    av4[k] = (v2f){0.4f * a0, 0.4f * a1};
    nu[k] = (v2f){0.f, 0.f};
  }
  float m = 0.f, s = 0.f;

  auto PROCESS = [&](const uint4& ra) {
    unsigned uu[4] = {ra.x, ra.y, ra.z, ra.w};
    v2f xlv[4];
    #pragma unroll
    for (int k = 0; k < 4; k++) xlv[k] = (v2f){bflo(uu[k]), bfhi(uu[k])};
    v2f e1 = (v2f){0.f, 0.f}, e2 = (v2f){0.f, 0.f};
    #pragma unroll
    for (int k = 0; k < 4; k++) {
      v2f z = xlv[k] + xrv[k];
      v2f za = (v2f){__builtin_fabsf(z.x), __builtin_fabsf(z.y)};
      e1 = av6[k] * z + e1;
      e2 = av4[k] * za + e2;
    }
    float e = e1.x + e1.y + e2.x + e2.y;
    if (e > m + 25.f) {
      float sc = __expf(m - e);
      s *= sc;
      v2f sc2 = (v2f){sc, sc};
      #pragma unroll
      for (int k = 0; k < 4; k++) nu[k] *= sc2;
      m = e;
    }
    float pe = __expf(e - m);
    s += pe;
    v2f pe2 = (v2f){pe, pe};
    #pragma unroll
    for (int k = 0; k < 4; k++) nu[k] = pe2 * xlv[k] + nu[k];
  };

  int i = beg + sub;
  int i3 = i + 24;
  int x3 = 0;
  uint4 r0, r1, r2;
  if (i < end)      r0 = reinterpret_cast<const uint4*>(xlb)[csr_src[i]];
  if (i + 8 < end)  r1 = reinterpret_cast<const uint4*>(xlb)[csr_src[i + 8]];
  if (i + 16 < end) r2 = reinterpret_cast<const uint4*>(xlb)[csr_src[i + 16]];
  if (i3 < end) x3 = csr_src[i3];

  #define STEP2(RR)                                                   \
    if (i >= end) break;                                              \
    PROCESS(RR);                                                      \
    if (i3 < end) RR = reinterpret_cast<const uint4*>(xlb)[x3];       \
    i += 8; i3 += 8;                                                  \
    if (i3 < end) x3 = csr_src[i3];

  for (;;) {
    STEP2(r0)
    STEP2(r1)
    STEP2(r2)
  }
  #undef STEP2

  float M = oct_max(m);
  float sc = __expf(m - M);
  float S = oct_sum(s * sc);
  float o[8];
  #pragma unroll
  for (int k = 0; k < 4; k++) {
    o[2*k]   = oct_sum(nu[k].x * sc);
    o[2*k+1] = oct_sum(nu[k].y * sc);
  }
  float inv = 1.f / fmaxf(S, 1e-16f);
  // each lane writes its own channel: 8 consecutive floats/node -> coalesced
  out[(long)node * 8 + sub] = fmaxf(o[sub] * inv + bias[sub], 0.f);
}

// ---------------- fused mean pool + linear: one block per graph ----------------
__global__ __launch_bounds__(256) void k_pool_final(const float* __restrict__ h,
    const int* __restrict__ batch, const float* __restrict__ Wlin,
    const float* __restrict__ blin, float* __restrict__ out, int n) {
  int g = blockIdx.x;
  int lo = 0, hi = n;
  while (lo < hi) { int mid = (lo + hi) >> 1; if (batch[mid] < g) lo = mid + 1; else hi = mid; }
  int beg = lo;
  hi = n;
  while (lo < hi) { int mid = (lo + hi) >> 1; if (batch[mid] < g + 1) lo = mid + 1; else hi = mid; }
  int end = lo;

  float w[8];
  #pragma unroll
  for (int c = 0; c < 8; c++) w[c] = Wlin[c];

  float acc = 0.f;
  int t = threadIdx.x;
  for (int i = beg + t; i < end; i += 256) {
    const float4* hp = reinterpret_cast<const float4*>(h + (long)i * 8);
    float4 v0 = hp[0], v1 = hp[1];
    acc += v0.x * w[0] + v0.y * w[1] + v0.z * w[2] + v0.w * w[3]
         + v1.x * w[4] + v1.y * w[5] + v1.z * w[6] + v1.w * w[7];
  }
  #pragma unroll
  for (int off = 32; off; off >>= 1) acc += __shfl_down(acc, off, 64);
  __shared__ float sh[4];
  if ((t & 63) == 0) sh[t >> 6] = acc;
  __syncthreads();
  if (t == 0) {
    float total = sh[0] + sh[1] + sh[2] + sh[3];
    float cnt = (float)(end - beg);
    out[g] = total / fmaxf(cnt, 1.f) + blin[0];
  }
}

extern "C" void kernel_launch(void* const* d_in, const int* in_sizes, int n_in,
                              void* d_out, int out_size, void* d_ws, size_t ws_size,
                              hipStream_t stream) {
  (void)n_in; (void)ws_size;
  const float* x    = (const float*)d_in[0];
  const int*   ei   = (const int*)d_in[1];
  const int*   batch= (const int*)d_in[2];
  const float* W1l  = (const float*)d_in[3];
  const float* W1r  = (const float*)d_in[4];
  const float* a1   = (const float*)d_in[5];
  const float* b1   = (const float*)d_in[6];
  const float* W2l  = (const float*)d_in[7];
  const float* W2r  = (const float*)d_in[8];
  const float* a2   = (const float*)d_in[9];
  const float* b2   = (const float*)d_in[10];
  const float* Wlin = (const float*)d_in[11];
  const float* blin = (const float*)d_in[12];
  float* out = (float*)d_out;

  int N = in_sizes[0] / 128;
  int E = in_sizes[1] / 2;
  int G = out_size;                 // 256 graphs
  int ET = E + N;                   // edges incl self loops
  int NBu = (N + 255) >> 8;         // used buckets (256 nodes each), <= NBS
  int chunk = (ET + NBLK - 1) / NBLK;
  int nA = NBS * NBLK;              // 131072

  char* ws = (char*)d_ws;
  size_t off = 0;
  auto alloc = [&](size_t bytes) {
    void* p = ws + off; off = (off + bytes + 255) & ~(size_t)255; return p;
  };
  int* csr_ptr = (int*)alloc((size_t)(N + 1) * 4);
  int* A       = (int*)alloc((size_t)(nA + 1) * 4);
  int* bsum    = (int*)alloc(512 * 4);
  int* csr_src = (int*)alloc((size_t)ET * 4);
  // union: packed pairs (ET*4 B) time-shared with feature buffers (N*176 B)
  size_t featBytes = (size_t)N * (32 + 64 + 16 + 32 + 32);
  size_t pairBytes = (size_t)ET * 4;
  char* u = (char*)alloc(pairBytes > featBytes ? pairBytes : featBytes);
  int* pairs = (int*)u;
  unsigned* xl1b = (unsigned*)u;                         // N*8 uints (bf16 x16)
  float* xr1     = (float*)(u + (size_t)N * 32);         // N*16 f32
  unsigned* xl2b = (unsigned*)(u + (size_t)N * 96);      // N*4 uints (bf16 x8)
  float* xr2     = (float*)(u + (size_t)N * 112);        // N*8 f32
  float* h2      = (float*)(u + (size_t)N * 144);        // N*8 f32

  k_bin_count<<<NBLK, 1024, 0, stream>>>(ei, E, ET, chunk, A);
  k_reduce4<<<nA / 1024, 256, 0, stream>>>(A, bsum, nA);
  k_scan_bsum<<<1, 512, 0, stream>>>(bsum, nA / 1024);
  k_scan_apply4<<<nA / 1024, 256, 0, stream>>>(A, bsum, nA);
  k_bin_scatter<<<NBLK, 1024, 0, stream>>>(ei, E, ET, chunk, A, pairs);
  k_csr_build<<<NBu, 1024, 0, stream>>>(pairs, A, csr_ptr, csr_src, N, NBu);
  k_gemm1<<<(N + 63) / 64, 256, 0, stream>>>(x, W1l, W1r, xl1b, xr1, N);
  k_edge1<<<(N + 31) / 32, 256, 0, stream>>>(csr_ptr, csr_src, xl1b, xr1, a1, b1,
                                             W2l, W2r, xl2b, xr2, N);
  k_edge2<<<(N + 31) / 32, 256, 0, stream>>>(csr_ptr, csr_src, xl2b, xr2, a2, b2, h2, N);
  k_pool_final<<<G, 256, 0, stream>>>(h2, batch, Wlin, blin, out, N);
}